// Round 1
// baseline (915.555 us; speedup 1.0000x reference)
//
#include <hip/hip_runtime.h>
#include <math.h>

#define HH 768
#define WW 768
#define NPIX (HH*WW)            // 589824
#define NRR 24
#define NCC 24
#define NCELL (NRR*NCC)         // 576
#define CTOPC 36
#define NB 2

// ws layout (float offsets)
#define OFF_WPK 0               // 24750 floats: repacked conv weights [ch][75][6]
#define OFF_FSUM 24750          // 2*576*18 = 20736
#define OFF_BOTP 45486          // 2*576 = 1152
#define OFF_TMEAN 46638         // 2*36*576 = 41472
#define OFF_PVAL 88110          // 576
#define OFF_BOUNDS 88686        // 96 ints: row_start[24] row_end[24] col_start[24] col_end[24]

// ---------------- Kernel 0: weight repack + segment bounds ----------------
__global__ void prep_kernel(const float* __restrict__ w1, const float* __restrict__ w2,
                            const float* __restrict__ w3,
                            const int* __restrict__ row_ids, const int* __restrict__ col_ids,
                            float* __restrict__ wpk, int* __restrict__ bounds) {
  int t = blockIdx.x * 256 + threadIdx.x;
  if (t < 24750) {
    int oc = t % 6; int q = t / 6;
    int tap = q % 25; q /= 25;
    int d = q % 3; int ch = q / 3;
    const float* wsrc = (d == 0) ? w1 : ((d == 1) ? w2 : w3);
    wpk[t] = wsrc[(oc * 55 + ch) * 25 + tap];
  }
  if (blockIdx.x == 0 && threadIdx.x < 48) {
    int tt = threadIdx.x;
    const int* ids = (tt < 24) ? row_ids : col_ids;
    int r = tt % 24;
    int s = HH, e = HH;
    for (int h = 0; h < HH; ++h) {
      int v = ids[h];
      if (v >= r && h < s) s = h;
      if (v >= r + 1 && h < e) e = h;
    }
    int base = (tt < 24) ? 0 : 48;
    bounds[base + r] = s;
    bounds[base + 24 + r] = e;
  }
}

// ---------------- Kernel A: 3x dilated 5x5 conv (18 out ch) + ReLU ----------------
// block = 512 threads -> 8x64 output tile; per-input-channel LDS staging (20x76 halo)
__global__ __launch_bounds__(512) void conv_kernel(const float* __restrict__ x,
    const float* __restrict__ wpk, const float* __restrict__ b1,
    const float* __restrict__ b2, const float* __restrict__ b3,
    float* __restrict__ out) {
  __shared__ float tile[20 * 76];
  int b = blockIdx.z;
  int h0 = blockIdx.y * 8;
  int w0 = blockIdx.x * 64;
  int tid = threadIdx.x;
  int ty = tid >> 6, tx = tid & 63;
  float acc[18];
  #pragma unroll
  for (int i = 0; i < 18; ++i) acc[i] = 0.f;
  const float* xb = x + (size_t)b * 55 * NPIX;
  for (int ch = 0; ch < 55; ++ch) {
    const float* xc = xb + (size_t)ch * NPIX;
    #pragma unroll
    for (int i = 0; i < 3; ++i) {
      int idx = tid + i * 512;
      if (idx < 20 * 76) {
        int rr = idx / 76, cc = idx % 76;
        int hh = h0 - 6 + rr, ww2 = w0 - 6 + cc;
        float v = 0.f;
        if ((unsigned)hh < 768u && (unsigned)ww2 < 768u) v = xc[hh * 768 + ww2];
        tile[idx] = v;
      }
    }
    __syncthreads();
    const float* wp = wpk + ch * 450;           // [75][6] for this channel
    const float* base = tile + (ty + 6) * 76 + tx + 6;
    #pragma unroll
    for (int d = 0; d < 3; ++d) {
      #pragma unroll
      for (int ky = 0; ky < 5; ++ky) {
        #pragma unroll
        for (int kx = 0; kx < 5; ++kx) {
          float v = base[((ky - 2) * 76 + (kx - 2)) * (d + 1)];
          const float* w6 = wp + (d * 25 + ky * 5 + kx) * 6;
          #pragma unroll
          for (int oc = 0; oc < 6; ++oc) acc[d * 6 + oc] += v * w6[oc];
        }
      }
    }
    __syncthreads();
  }
  int h = h0 + ty, w = w0 + tx;
  int pix = h * 768 + w;
  float* ob = out + ((size_t)b * 55 + 36) * NPIX + pix;
  #pragma unroll
  for (int d = 0; d < 3; ++d) {
    const float* bb = (d == 0) ? b1 : ((d == 1) ? b2 : b3);
    #pragma unroll
    for (int oc = 0; oc < 6; ++oc) {
      float v = acc[d * 6 + oc] + bb[oc];
      ob[(size_t)(d * 6 + oc) * NPIX] = v > 0.f ? v : 0.f;
    }
  }
}

// ---------------- Kernel B: per-cell sums of features + sigmoid(bot) ----------------
__global__ __launch_bounds__(256) void cellsum_kernel(const float* __restrict__ dout,
    const int* __restrict__ bounds,
    const float* __restrict__ w_bot, const float* __restrict__ b_bot,
    float* __restrict__ feat_sums, float* __restrict__ bot_partial) {
  int blk = blockIdx.x;                       // b*576 + r*24 + c
  int b = blk / NCELL; int rc = blk % NCELL; int r = rc / NCC, c = rc % NCC;
  int rs = bounds[r], re = bounds[24 + r], cs = bounds[48 + c], ce = bounds[72 + c];
  int cw = ce - cs;
  int npix = (re - rs) * cw;
  float facc[18];
  #pragma unroll
  for (int k = 0; k < 18; ++k) facc[k] = 0.f;
  float sacc = 0.f;
  float wb[18];
  #pragma unroll
  for (int k = 0; k < 18; ++k) wb[k] = w_bot[k];
  float bb = b_bot[0];
  const float* fb = dout + ((size_t)b * 55 + 36) * NPIX;
  for (int i = threadIdx.x; i < npix; i += 256) {
    int hh = rs + i / cw, ww = cs + i % cw;
    int pix = hh * WW + ww;
    float dot = bb;
    #pragma unroll
    for (int k = 0; k < 18; ++k) {
      float v = fb[(size_t)k * NPIX + pix];
      facc[k] += v;
      dot += wb[k] * v;
    }
    sacc += 1.f / (1.f + expf(-dot));
  }
  #pragma unroll
  for (int k = 0; k < 18; ++k) {
    #pragma unroll
    for (int off = 32; off; off >>= 1) facc[k] += __shfl_xor(facc[k], off);
  }
  #pragma unroll
  for (int off = 32; off; off >>= 1) sacc += __shfl_xor(sacc, off);
  __shared__ float red[4][19];
  int wv = threadIdx.x >> 6, ln = threadIdx.x & 63;
  if (ln == 0) {
    #pragma unroll
    for (int k = 0; k < 18; ++k) red[wv][k] = facc[k];
    red[wv][18] = sacc;
  }
  __syncthreads();
  if (threadIdx.x < 19) {
    float s = red[0][threadIdx.x] + red[1][threadIdx.x] + red[2][threadIdx.x] + red[3][threadIdx.x];
    if (threadIdx.x < 18) feat_sums[(size_t)blk * 18 + threadIdx.x] = s;
    else bot_partial[blk] = s;
  }
}

// ---------------- Kernel C: cell means (top) + pools ----------------
__global__ void cellmean_kernel(const float* __restrict__ feat_sums,
    const float* __restrict__ bot_partial, const int* __restrict__ bounds,
    const float* __restrict__ w_top, const float* __restrict__ b_top,
    float* __restrict__ top_means, float* __restrict__ pools_val, float* __restrict__ dout) {
  int t = blockIdx.x * 256 + threadIdx.x;
  if (t < NB * CTOPC * NCELL) {
    int c = t % NCC, r = (t / NCC) % NRR, k = (t / NCELL) % CTOPC, b = t / (NCELL * CTOPC);
    int cnt = (bounds[24 + r] - bounds[r]) * (bounds[72 + c] - bounds[48 + c]);
    float v = 0.f;
    if (cnt > 0) {
      const float* fs = feat_sums + ((size_t)(b * NCELL + r * NCC + c)) * 18;
      float dot = 0.f;
      #pragma unroll
      for (int i = 0; i < 18; ++i) dot += w_top[k * 18 + i] * fs[i];
      v = dot / (float)cnt + b_top[k];
    }
    top_means[t] = v;   // [b][k][r][c]
  }
  int t2 = t - NB * CTOPC * NCELL;
  if (t2 >= 0 && t2 < NCELL) {
    int r = t2 / NCC, c = t2 % NCC;
    int cnt = (bounds[24 + r] - bounds[r]) * (bounds[72 + c] - bounds[48 + c]);
    if (cnt < 1) cnt = 1;
    float v = (bot_partial[t2] + bot_partial[NCELL + t2]) / (2.f * (float)cnt);
    pools_val[t2] = v;
    dout[(size_t)NB * 55 * NPIX + t2] = v;           // pools b=0
    dout[(size_t)NB * 55 * NPIX + NCELL + t2] = v;   // pools b=1
  }
}

// ---------------- Kernel D: broadcast top means + bottom value ----------------
__global__ __launch_bounds__(256) void bcast_kernel(const float* __restrict__ top_means,
    const float* __restrict__ pools_val, const int* __restrict__ row_ids,
    const int* __restrict__ col_ids, float* __restrict__ out) {
  int w = blockIdx.x * 256 + threadIdx.x;
  int h = blockIdx.y;
  int b = blockIdx.z;
  int r = row_ids[h], c = col_ids[w];
  int pix = h * 768 + w;
  float* ob = out + (size_t)b * 55 * NPIX + pix;
  const float* tm = top_means + (size_t)b * CTOPC * NCELL + r * NCC + c;
  #pragma unroll
  for (int k = 0; k < 36; ++k) ob[(size_t)k * NPIX] = tm[(size_t)k * NCELL];
  ob[(size_t)54 * NPIX] = pools_val[r * NCC + c];
}

extern "C" void kernel_launch(void* const* d_in, const int* in_sizes, int n_in,
                              void* d_out, int out_size, void* d_ws, size_t ws_size,
                              hipStream_t stream) {
  const float* x      = (const float*)d_in[0];
  const int* row_ids  = (const int*)d_in[1];
  const int* col_ids  = (const int*)d_in[2];
  const float* w1     = (const float*)d_in[5];
  const float* b1     = (const float*)d_in[6];
  const float* w2     = (const float*)d_in[7];
  const float* b2     = (const float*)d_in[8];
  const float* w3     = (const float*)d_in[9];
  const float* b3     = (const float*)d_in[10];
  const float* w_top  = (const float*)d_in[11];
  const float* b_top  = (const float*)d_in[12];
  const float* w_bot  = (const float*)d_in[13];
  const float* b_bot  = (const float*)d_in[14];
  float* out = (float*)d_out;
  float* ws  = (float*)d_ws;

  float* wpk        = ws + OFF_WPK;
  float* feat_sums  = ws + OFF_FSUM;
  float* bot_partial= ws + OFF_BOTP;
  float* top_means  = ws + OFF_TMEAN;
  float* pools_val  = ws + OFF_PVAL;
  int*   bounds     = (int*)(ws + OFF_BOUNDS);

  hipLaunchKernelGGL(prep_kernel, dim3(97), dim3(256), 0, stream,
                     w1, w2, w3, row_ids, col_ids, wpk, bounds);
  hipLaunchKernelGGL(conv_kernel, dim3(12, 96, 2), dim3(512), 0, stream,
                     x, wpk, b1, b2, b3, out);
  hipLaunchKernelGGL(cellsum_kernel, dim3(NB * NCELL), dim3(256), 0, stream,
                     out, bounds, w_bot, b_bot, feat_sums, bot_partial);
  hipLaunchKernelGGL(cellmean_kernel, dim3(165), dim3(256), 0, stream,
                     feat_sums, bot_partial, bounds, w_top, b_top, top_means, pools_val, out);
  hipLaunchKernelGGL(bcast_kernel, dim3(3, 768, 2), dim3(256), 0, stream,
                     top_means, pools_val, row_ids, col_ids, out);
}